// Round 6
// baseline (153.096 us; speedup 1.0000x reference)
//
#include <hip/hip_runtime.h>

// Chamfer distance, fp32, FUSED brute force: each pair d(p_i,t_j) computed
// ONCE (268M pairs, not 537M) and folded into BOTH the predict-row min and
// the target-col min.
//   rows (per-lane, P=8): predict points. s = tt - 2 p.t via 3 fma (addend tw).
//     row-min: min3(mn, s0, s1). reduce_kernel later adds pp.
//   cols: u = s + pp = full d. per-lane min3-tree over P rows, then 2-step
//     DPP quad butterfly (VALU pipe, no LDS), owner lane (lane&3)==(c&3),
//     one coalesced no-return atomicMin per 4 columns (order-independent
//     min on monotone keys -> bit-exact deterministic).
// Column delivery: forced s_load_dwordx4 batches (8 cols -> 32 SGPRs) +
// single lgkmcnt(0) per batch (SMEM completes out of order). Zero LDS.

#define NPTS   8192
#define HALF   32768            // 4 * NPTS
#define NROWS  65536
#define P      8                // predict rows per thread
#define RPB    2048             // rows per block = 256 * P
#define NRB_B  4                // row-blocks per batch
#define CW     64               // target cols per block
#define NCH    128              // col chunks per batch
// grid = 4 batches * NRB_B * NCH = 2048 blocks

typedef float sfloat4 __attribute__((ext_vector_type(4)));

__device__ __forceinline__ void min3t(float& a, float b, float c) {
    asm("v_min3_f32 %0, %0, %1, %2" : "+v"(a) : "v"(b), "v"(c));
}
__device__ __forceinline__ float min3v(float a, float b, float c) {
    float d;
    asm("v_min3_f32 %0, %1, %2, %3" : "=v"(d) : "v"(a), "v"(b), "v"(c));
    return d;
}
__device__ __forceinline__ unsigned int fkey(float f) {
    unsigned int b = __float_as_uint(f);
    return b ^ (0x80000000u | (unsigned int)((int)b >> 31));
}
__device__ __forceinline__ float funkey(unsigned int k) {
    unsigned int b = (k & 0x80000000u) ? (k ^ 0x80000000u) : ~k;
    return __uint_as_float(b);
}

__global__ __launch_bounds__(256) void pack_kernel(
    const float* __restrict__ predict, const float* __restrict__ target,
    float4* __restrict__ packed, unsigned int* __restrict__ rowmin)
{
    int r = blockIdx.x * 256 + threadIdx.x;
    const float* src = (r < HALF) ? (predict + (size_t)r * 3)
                                  : (target + (size_t)(r - HALF) * 3);
    float x = src[0], y = src[1], z = src[2];
    float nrm = fmaf(x, x, fmaf(y, y, z * z));
    packed[r] = make_float4(x, y, z, nrm);
    rowmin[r] = 0xFFFFFFFFu;                  // +inf key
}

// one column pair: row-min update + per-lane col trees LA (col a), LB (col b)
#define PAIR(ta, tb, LA, LB) do {                                             \
    float sA[P], sB[P];                                                       \
    float twA = (ta).w, twB = (tb).w;                                         \
    _Pragma("unroll")                                                         \
    for (int j = 0; j < P; ++j) {                                             \
        sA[j] = fmaf(qx[j], (ta).x, fmaf(qy[j], (ta).y, fmaf(qz[j], (ta).z, twA))); \
        sB[j] = fmaf(qx[j], (tb).x, fmaf(qy[j], (tb).y, fmaf(qz[j], (tb).z, twB))); \
    }                                                                         \
    _Pragma("unroll")                                                         \
    for (int j = 0; j < P; ++j) min3t(mn[j], sA[j], sB[j]);                   \
    _Pragma("unroll")                                                         \
    for (int j = 0; j < P; ++j) { sA[j] += pp[j]; sB[j] += pp[j]; }           \
    { float a = min3v(sA[0],sA[1],sA[2]); float b = min3v(sA[3],sA[4],sA[5]); \
      a = min3v(a, b, sA[6]); LA = fminf(a, sA[7]); }                         \
    { float a = min3v(sB[0],sB[1],sB[2]); float b = min3v(sB[3],sB[4],sB[5]); \
      a = min3v(a, b, sB[6]); LB = fminf(a, sB[7]); }                         \
} while (0)

// quad of 4 columns: DPP butterfly over quads + owner select + 1 atomic
#define QUAD(ta, tb, tc, td, tIdx) do {                                       \
    float L0, L1, L2, L3;                                                     \
    PAIR(ta, tb, L0, L1);                                                     \
    PAIR(tc, td, L2, L3);                                                     \
    float g0, g1, g2, g3, acc;                                                \
    asm volatile(                                                             \
        "s_nop 1\n\t"                                                         \
        "v_min_f32 %0, %5, %5 quad_perm:[1,0,3,2] row_mask:0xf bank_mask:0xf\n\t" \
        "v_min_f32 %1, %6, %6 quad_perm:[1,0,3,2] row_mask:0xf bank_mask:0xf\n\t" \
        "v_min_f32 %2, %7, %7 quad_perm:[1,0,3,2] row_mask:0xf bank_mask:0xf\n\t" \
        "v_min_f32 %3, %8, %8 quad_perm:[1,0,3,2] row_mask:0xf bank_mask:0xf\n\t" \
        "v_min_f32 %0, %0, %0 quad_perm:[2,3,0,1] row_mask:0xf bank_mask:0xf\n\t" \
        "v_min_f32 %1, %1, %1 quad_perm:[2,3,0,1] row_mask:0xf bank_mask:0xf\n\t" \
        "v_min_f32 %2, %2, %2 quad_perm:[2,3,0,1] row_mask:0xf bank_mask:0xf\n\t" \
        "v_min_f32 %3, %3, %3 quad_perm:[2,3,0,1] row_mask:0xf bank_mask:0xf\n\t" \
        "v_cmp_eq_u32 vcc, 0, %9\n\t"                                         \
        "v_cndmask_b32 %4, %10, %0, vcc\n\t"                                  \
        "v_cmp_eq_u32 vcc, 1, %9\n\t"                                         \
        "v_cndmask_b32 %4, %4, %1, vcc\n\t"                                   \
        "v_cmp_eq_u32 vcc, 2, %9\n\t"                                         \
        "v_cndmask_b32 %4, %4, %2, vcc\n\t"                                   \
        "v_cmp_eq_u32 vcc, 3, %9\n\t"                                         \
        "v_cndmask_b32 %4, %4, %3, vcc"                                       \
        : "=&v"(g0), "=&v"(g1), "=&v"(g2), "=&v"(g3), "=&v"(acc)              \
        : "v"(L0), "v"(L1), "v"(L2), "v"(L3), "v"(lane3), "v"(INFV)           \
        : "vcc");                                                             \
    atomicMin(rowmin + (tIdx) + lane3, fkey(acc));                            \
} while (0)

__global__ __launch_bounds__(256, 4) void minpart_kernel(
    const float4* __restrict__ packed, unsigned int* __restrict__ rowmin)
{
    const int bid   = blockIdx.x;
    const int batch = bid >> 9;               // / (NRB_B*NCH)
    const int rem   = bid & 511;
    const int rb    = rem >> 7;               // / NCH
    const int cb    = rem & 127;

    const int prow0 = batch * NPTS + rb * RPB;     // predict row base (< HALF)
    const int tcol0 = batch * NPTS + cb * CW;      // target col base (in half)
    const float4* __restrict__ cbase = packed + (HALF + tcol0);
    const int tid   = threadIdx.x;
    const int lane3 = tid & 3;
    const float INFV = 3.4e38f;

    float qx[P], qy[P], qz[P], pp[P], mn[P];
    #pragma unroll
    for (int j = 0; j < P; ++j) {
        float4 p = packed[prow0 + tid + j * 256];
        qx[j] = -2.0f * p.x; qy[j] = -2.0f * p.y; qz[j] = -2.0f * p.z;
        pp[j] = p.w; mn[j] = 3.4e38f;
    }

    #pragma unroll 1
    for (int g8 = 0; g8 < CW / 8; ++g8) {
        const float4* cp = cbase + g8 * 8;
        sfloat4 t0, t1, t2, t3, t4, t5, t6, t7;
        asm volatile(
            "s_load_dwordx4 %0, %8, 0x0\n\t"
            "s_load_dwordx4 %1, %8, 0x10\n\t"
            "s_load_dwordx4 %2, %8, 0x20\n\t"
            "s_load_dwordx4 %3, %8, 0x30\n\t"
            "s_load_dwordx4 %4, %8, 0x40\n\t"
            "s_load_dwordx4 %5, %8, 0x50\n\t"
            "s_load_dwordx4 %6, %8, 0x60\n\t"
            "s_load_dwordx4 %7, %8, 0x70\n\t"
            "s_waitcnt lgkmcnt(0)"
            : "=s"(t0), "=s"(t1), "=s"(t2), "=s"(t3),
              "=s"(t4), "=s"(t5), "=s"(t6), "=s"(t7)
            : "s"(cp));

        const int tIdx0 = HALF + tcol0 + g8 * 8;   // rowmin index of col 0
        QUAD(t0, t1, t2, t3, tIdx0);
        QUAD(t4, t5, t6, t7, tIdx0 + 4);
    }

    #pragma unroll
    for (int j = 0; j < P; ++j)
        atomicMin(&rowmin[prow0 + tid + j * 256], fkey(mn[j]));
}

__global__ __launch_bounds__(256) void reduce_kernel(
    const float4* __restrict__ packed, const unsigned int* __restrict__ rowmin,
    float* __restrict__ blockSums)
{
    int r = blockIdx.x * 256 + threadIdx.x;
    // predict rows stored min(tt-2pt): add pp. target rows stored full d.
    float add = (r < HALF) ? packed[r].w : 0.0f;
    float val = funkey(rowmin[r]) + add;

    __shared__ float red[256];
    red[threadIdx.x] = val;
    __syncthreads();
    for (int s = 128; s > 0; s >>= 1) {
        if (threadIdx.x < s) red[threadIdx.x] += red[threadIdx.x + s];
        __syncthreads();
    }
    if (threadIdx.x == 0) blockSums[blockIdx.x] = red[0];
}

__global__ __launch_bounds__(256) void final_kernel(
    const float* __restrict__ blockSums, float* __restrict__ out)
{
    __shared__ float red[256];
    red[threadIdx.x] = blockSums[threadIdx.x];
    __syncthreads();
    for (int s = 128; s > 0; s >>= 1) {
        if (threadIdx.x < s) red[threadIdx.x] += red[threadIdx.x + s];
        __syncthreads();
    }
    if (threadIdx.x == 0) out[0] = red[0] * (1.0f / (float)HALF);
}

extern "C" void kernel_launch(void* const* d_in, const int* in_sizes, int n_in,
                              void* d_out, int out_size, void* d_ws, size_t ws_size,
                              hipStream_t stream)
{
    const float* predict = (const float*)d_in[0];
    const float* target  = (const float*)d_in[1];
    float* out = (float*)d_out;

    char* ws = (char*)d_ws;
    float4*       packed    = (float4*)ws;                              // 1 MB
    unsigned int* rowmin    = (unsigned int*)(ws + (size_t)NROWS * 16); // 256 KB
    float*        blockSums = (float*)(ws + (size_t)NROWS * 16
                                          + (size_t)NROWS * 4);         // 1 KB

    pack_kernel   <<<NROWS / 256,        256, 0, stream>>>(predict, target, packed, rowmin);
    minpart_kernel<<<4 * NRB_B * NCH,    256, 0, stream>>>(packed, rowmin);
    reduce_kernel <<<NROWS / 256,        256, 0, stream>>>(packed, rowmin, blockSums);
    final_kernel  <<<1,                  256, 0, stream>>>(blockSums, out);
}

// Round 9
// 64.771 us; speedup vs baseline: 2.3636x; 2.3636x over previous
//
#include <hip/hip_runtime.h>

// Chamfer distance, fp32 brute force, row-min only (537M pairs), VALU-bound.
// rows 0..32767    : predict points (b = r>>13), cols = target[b]
// rows 32768..65535: target points,              cols = predict[b]
// Per row: min over 8192 cols of (||t||^2 - 2 p.t), then + ||p||^2 (reduce).
// out = (sum over all 65536 rows) / 32768.
//
// Columns are wave-uniform -> delivered via explicit s_load_dwordx4 batches
// (8 cols = 32 SGPRs) with the single s_waitcnt lgkmcnt(0) INSIDE the asm
// block (SMEM completes OUT OF ORDER: counted lgkmcnt(N) is unsafe for
// s_load — R8's lgkmcnt(4) "hardening" returned inf). Zero LDS, zero
// per-lane VMEM in the hot loop (R3: LDS pipe at ~86% of the VALU window
// was the stall source; R5 proved this asm path bit-exact).
// 8 waves/SIMD via __launch_bounds__(256,8) hide K$ latency.
// Inner: q=-2p; s = fma(qx,tx, fma(qy,ty, fma(qz,tz, tw))); v_min3_f32
// folds 2 cols. ~3.6 VALU/pair -> ~25us issue floor.
// Cross-chunk combine: deterministic atomicMin on monotone uint keys,
// per-lane distinct addresses (coalesced, no same-address serialization).

#define NPTS   8192
#define HALF   32768            // 4 * NPTS
#define NROWS  65536
#define P      8                // rows per thread (32 VGPR row state)
#define RPB    2048             // rows per block = 256 * P
#define NRB    32               // NROWS / RPB
#define NCH    64               // col chunks -> 2048 blocks = 8/CU
#define CW     (NPTS / NCH)     // 128 cols per chunk

typedef float sfloat4 __attribute__((ext_vector_type(4)));

__device__ __forceinline__ void min3t(float& a, float b, float c) {
    asm("v_min3_f32 %0, %0, %1, %2" : "+v"(a) : "v"(b), "v"(c));
}
__device__ __forceinline__ unsigned int fkey(float f) {
    unsigned int b = __float_as_uint(f);
    return b ^ (0x80000000u | (unsigned int)((int)b >> 31));
}
__device__ __forceinline__ float funkey(unsigned int k) {
    unsigned int b = (k & 0x80000000u) ? (k ^ 0x80000000u) : ~k;
    return __uint_as_float(b);
}

__global__ __launch_bounds__(256) void pack_kernel(
    const float* __restrict__ predict, const float* __restrict__ target,
    float4* __restrict__ packed, unsigned int* __restrict__ rowmin)
{
    int r = blockIdx.x * 256 + threadIdx.x;
    const float* src = (r < HALF) ? (predict + (size_t)r * 3)
                                  : (target + (size_t)(r - HALF) * 3);
    float x = src[0], y = src[1], z = src[2];
    float nrm = fmaf(x, x, fmaf(y, y, z * z));
    packed[r] = make_float4(x, y, z, nrm);
    rowmin[r] = 0xFFFFFFFFu;                  // +inf key
}

// 2 columns folded into the P row-mins: 6 fma + 1 min3 per row
#define COLPAIR(ta, tb) do {                                                  \
    float twA = (ta).w, twB = (tb).w;                                         \
    _Pragma("unroll")                                                         \
    for (int j = 0; j < P; ++j) {                                             \
        float sA = fmaf(qx[j], (ta).x, fmaf(qy[j], (ta).y, fmaf(qz[j], (ta).z, twA))); \
        float sB = fmaf(qx[j], (tb).x, fmaf(qy[j], (tb).y, fmaf(qz[j], (tb).z, twB))); \
        min3t(mn[j], sA, sB);                                                 \
    }                                                                         \
} while (0)

__global__ __launch_bounds__(256, 8) void minpart_kernel(
    const float4* __restrict__ packed, unsigned int* __restrict__ rowmin)
{
    const int rb   = blockIdx.x / NCH;
    const int cb   = blockIdx.x % NCH;
    const int row0 = rb * RPB;
    const bool sideA = (row0 < HALF);
    const int local = sideA ? row0 : row0 - HALF;
    const int b = local >> 13;                // / NPTS
    const float4* __restrict__ cbase =
        packed + ((sideA ? HALF : 0) + (b << 13) + cb * CW);
    const int tid = threadIdx.x;

    float qx[P], qy[P], qz[P], mn[P];
    #pragma unroll
    for (int j = 0; j < P; ++j) {
        float4 p = packed[row0 + tid + j * 256];
        qx[j] = -2.0f * p.x; qy[j] = -2.0f * p.y; qz[j] = -2.0f * p.z;
        mn[j] = 3.4e38f;
    }

    #pragma unroll 1
    for (int g = 0; g < CW / 8; ++g) {
        const float4* cp = cbase + g * 8;
        sfloat4 t0, t1, t2, t3, t4, t5, t6, t7;
        asm volatile(
            "s_load_dwordx4 %0, %8, 0x0\n\t"
            "s_load_dwordx4 %1, %8, 0x10\n\t"
            "s_load_dwordx4 %2, %8, 0x20\n\t"
            "s_load_dwordx4 %3, %8, 0x30\n\t"
            "s_load_dwordx4 %4, %8, 0x40\n\t"
            "s_load_dwordx4 %5, %8, 0x50\n\t"
            "s_load_dwordx4 %6, %8, 0x60\n\t"
            "s_load_dwordx4 %7, %8, 0x70\n\t"
            "s_waitcnt lgkmcnt(0)"
            : "=s"(t0), "=s"(t1), "=s"(t2), "=s"(t3),
              "=s"(t4), "=s"(t5), "=s"(t6), "=s"(t7)
            : "s"(cp));

        COLPAIR(t0, t1);
        COLPAIR(t2, t3);
        COLPAIR(t4, t5);
        COLPAIR(t6, t7);
    }

    #pragma unroll
    for (int j = 0; j < P; ++j)
        atomicMin(&rowmin[row0 + tid + j * 256], fkey(mn[j]));
}

__global__ __launch_bounds__(256) void reduce_kernel(
    const float4* __restrict__ packed, const unsigned int* __restrict__ rowmin,
    float* __restrict__ blockSums)
{
    int r = blockIdx.x * 256 + threadIdx.x;
    float val = funkey(rowmin[r]) + packed[r].w;   // + own ||.||^2

    __shared__ float red[256];
    red[threadIdx.x] = val;
    __syncthreads();
    for (int s = 128; s > 0; s >>= 1) {
        if (threadIdx.x < s) red[threadIdx.x] += red[threadIdx.x + s];
        __syncthreads();
    }
    if (threadIdx.x == 0) blockSums[blockIdx.x] = red[0];
}

__global__ __launch_bounds__(256) void final_kernel(
    const float* __restrict__ blockSums, float* __restrict__ out)
{
    __shared__ float red[256];
    red[threadIdx.x] = blockSums[threadIdx.x];
    __syncthreads();
    for (int s = 128; s > 0; s >>= 1) {
        if (threadIdx.x < s) red[threadIdx.x] += red[threadIdx.x + s];
        __syncthreads();
    }
    if (threadIdx.x == 0) out[0] = red[0] * (1.0f / (float)HALF);
}

extern "C" void kernel_launch(void* const* d_in, const int* in_sizes, int n_in,
                              void* d_out, int out_size, void* d_ws, size_t ws_size,
                              hipStream_t stream)
{
    const float* predict = (const float*)d_in[0];
    const float* target  = (const float*)d_in[1];
    float* out = (float*)d_out;

    char* ws = (char*)d_ws;
    float4*       packed    = (float4*)ws;                              // 1 MB
    unsigned int* rowmin    = (unsigned int*)(ws + (size_t)NROWS * 16); // 256 KB
    float*        blockSums = (float*)(ws + (size_t)NROWS * 16
                                          + (size_t)NROWS * 4);         // 1 KB

    pack_kernel   <<<NROWS / 256, 256, 0, stream>>>(predict, target, packed, rowmin);
    minpart_kernel<<<NRB * NCH,   256, 0, stream>>>(packed, rowmin);
    reduce_kernel <<<NROWS / 256, 256, 0, stream>>>(packed, rowmin, blockSums);
    final_kernel  <<<1,           256, 0, stream>>>(blockSums, out);
}

// Round 11
// 63.454 us; speedup vs baseline: 2.4127x; 1.0207x over previous
//
#include <hip/hip_runtime.h>

// Chamfer distance, fp32 brute force, row-min only (537M pairs), VALU-bound.
// rows 0..32767    : predict points (b = r>>13), cols = target[b]
// rows 32768..65535: target points,              cols = predict[b]
// Per row: min over 8192 cols of (||t||^2 - 2 p.t), then + ||p||^2 (reduce).
// out = (sum over all 65536 rows) / 32768.
//
// Columns are wave-uniform -> explicit s_load_dwordx4 batches (8 cols = 32
// SGPRs) with the single s_waitcnt lgkmcnt(0) INSIDE the asm block (SMEM
// completes OUT OF ORDER — counted lgkmcnt(N) on s_load returned inf in R8).
// Zero LDS, zero per-lane VMEM in the hot loop.
// __launch_bounds__(256,4): VGPR cap 128. R9 used (256,8) (cap 64) and
// regalloc REMATERIALIZED the 32-reg row state by re-loading from global
// inside the loop (VGPR_Count=20, 58.9us). R5 proved this exact asm block
// + row state stays resident at cap 128 (VGPR=64).
// Inner: q=-2p; s = fma(qx,tx, fma(qy,ty, fma(qz,tz, tw))); v_min3_f32
// folds 2 cols. ~3.6 VALU/pair -> ~25us issue floor.
// Cross-chunk combine: deterministic atomicMin on monotone uint keys,
// per-lane distinct addresses (coalesced).
// (R10 submission of this exact kernel died to container infra — verbatim
// re-run to preserve the single-variable A/B vs R9.)

#define NPTS   8192
#define HALF   32768            // 4 * NPTS
#define NROWS  65536
#define P      8                // rows per thread (32 VGPR row state)
#define RPB    2048             // rows per block = 256 * P
#define NRB    32               // NROWS / RPB
#define NCH    64               // col chunks -> 2048 blocks = 8/CU
#define CW     (NPTS / NCH)     // 128 cols per chunk

typedef float sfloat4 __attribute__((ext_vector_type(4)));

__device__ __forceinline__ void min3t(float& a, float b, float c) {
    asm("v_min3_f32 %0, %0, %1, %2" : "+v"(a) : "v"(b), "v"(c));
}
__device__ __forceinline__ unsigned int fkey(float f) {
    unsigned int b = __float_as_uint(f);
    return b ^ (0x80000000u | (unsigned int)((int)b >> 31));
}
__device__ __forceinline__ float funkey(unsigned int k) {
    unsigned int b = (k & 0x80000000u) ? (k ^ 0x80000000u) : ~k;
    return __uint_as_float(b);
}

__global__ __launch_bounds__(256) void pack_kernel(
    const float* __restrict__ predict, const float* __restrict__ target,
    float4* __restrict__ packed, unsigned int* __restrict__ rowmin)
{
    int r = blockIdx.x * 256 + threadIdx.x;
    const float* src = (r < HALF) ? (predict + (size_t)r * 3)
                                  : (target + (size_t)(r - HALF) * 3);
    float x = src[0], y = src[1], z = src[2];
    float nrm = fmaf(x, x, fmaf(y, y, z * z));
    packed[r] = make_float4(x, y, z, nrm);
    rowmin[r] = 0xFFFFFFFFu;                  // +inf key
}

// 2 columns folded into the P row-mins: 6 fma + 1 min3 per row
#define COLPAIR(ta, tb) do {                                                  \
    float twA = (ta).w, twB = (tb).w;                                         \
    _Pragma("unroll")                                                         \
    for (int j = 0; j < P; ++j) {                                             \
        float sA = fmaf(qx[j], (ta).x, fmaf(qy[j], (ta).y, fmaf(qz[j], (ta).z, twA))); \
        float sB = fmaf(qx[j], (tb).x, fmaf(qy[j], (tb).y, fmaf(qz[j], (tb).z, twB))); \
        min3t(mn[j], sA, sB);                                                 \
    }                                                                         \
} while (0)

__global__ __launch_bounds__(256, 4) void minpart_kernel(
    const float4* __restrict__ packed, unsigned int* __restrict__ rowmin)
{
    const int rb   = blockIdx.x / NCH;
    const int cb   = blockIdx.x % NCH;
    const int row0 = rb * RPB;
    const bool sideA = (row0 < HALF);
    const int local = sideA ? row0 : row0 - HALF;
    const int b = local >> 13;                // / NPTS
    const float4* __restrict__ cbase =
        packed + ((sideA ? HALF : 0) + (b << 13) + cb * CW);
    const int tid = threadIdx.x;

    float qx[P], qy[P], qz[P], mn[P];
    #pragma unroll
    for (int j = 0; j < P; ++j) {
        float4 p = packed[row0 + tid + j * 256];
        qx[j] = -2.0f * p.x; qy[j] = -2.0f * p.y; qz[j] = -2.0f * p.z;
        mn[j] = 3.4e38f;
    }

    #pragma unroll 1
    for (int g = 0; g < CW / 8; ++g) {
        const float4* cp = cbase + g * 8;
        sfloat4 t0, t1, t2, t3, t4, t5, t6, t7;
        asm volatile(
            "s_load_dwordx4 %0, %8, 0x0\n\t"
            "s_load_dwordx4 %1, %8, 0x10\n\t"
            "s_load_dwordx4 %2, %8, 0x20\n\t"
            "s_load_dwordx4 %3, %8, 0x30\n\t"
            "s_load_dwordx4 %4, %8, 0x40\n\t"
            "s_load_dwordx4 %5, %8, 0x50\n\t"
            "s_load_dwordx4 %6, %8, 0x60\n\t"
            "s_load_dwordx4 %7, %8, 0x70\n\t"
            "s_waitcnt lgkmcnt(0)"
            : "=s"(t0), "=s"(t1), "=s"(t2), "=s"(t3),
              "=s"(t4), "=s"(t5), "=s"(t6), "=s"(t7)
            : "s"(cp));

        COLPAIR(t0, t1);
        COLPAIR(t2, t3);
        COLPAIR(t4, t5);
        COLPAIR(t6, t7);
    }

    #pragma unroll
    for (int j = 0; j < P; ++j)
        atomicMin(&rowmin[row0 + tid + j * 256], fkey(mn[j]));
}

__global__ __launch_bounds__(256) void reduce_kernel(
    const float4* __restrict__ packed, const unsigned int* __restrict__ rowmin,
    float* __restrict__ blockSums)
{
    int r = blockIdx.x * 256 + threadIdx.x;
    float val = funkey(rowmin[r]) + packed[r].w;   // + own ||.||^2

    __shared__ float red[256];
    red[threadIdx.x] = val;
    __syncthreads();
    for (int s = 128; s > 0; s >>= 1) {
        if (threadIdx.x < s) red[threadIdx.x] += red[threadIdx.x + s];
        __syncthreads();
    }
    if (threadIdx.x == 0) blockSums[blockIdx.x] = red[0];
}

__global__ __launch_bounds__(256) void final_kernel(
    const float* __restrict__ blockSums, float* __restrict__ out)
{
    __shared__ float red[256];
    red[threadIdx.x] = blockSums[threadIdx.x];
    __syncthreads();
    for (int s = 128; s > 0; s >>= 1) {
        if (threadIdx.x < s) red[threadIdx.x] += red[threadIdx.x + s];
        __syncthreads();
    }
    if (threadIdx.x == 0) out[0] = red[0] * (1.0f / (float)HALF);
}

extern "C" void kernel_launch(void* const* d_in, const int* in_sizes, int n_in,
                              void* d_out, int out_size, void* d_ws, size_t ws_size,
                              hipStream_t stream)
{
    const float* predict = (const float*)d_in[0];
    const float* target  = (const float*)d_in[1];
    float* out = (float*)d_out;

    char* ws = (char*)d_ws;
    float4*       packed    = (float4*)ws;                              // 1 MB
    unsigned int* rowmin    = (unsigned int*)(ws + (size_t)NROWS * 16); // 256 KB
    float*        blockSums = (float*)(ws + (size_t)NROWS * 16
                                          + (size_t)NROWS * 4);         // 1 KB

    pack_kernel   <<<NROWS / 256, 256, 0, stream>>>(predict, target, packed, rowmin);
    minpart_kernel<<<NRB * NCH,   256, 0, stream>>>(packed, rowmin);
    reduce_kernel <<<NROWS / 256, 256, 0, stream>>>(packed, rowmin, blockSums);
    final_kernel  <<<1,           256, 0, stream>>>(blockSums, out);
}